// Round 14
// baseline (50.265 us; speedup 1.0000x reference)
//
#include <hip/hip_runtime.h>
#include <stdint.h>

#define HH 224
#define WW 224
#define NSEAM 7
#define BWIDTH 5
#define BB 256
#define KK 64
#define YCH 8
#define YROWS (HH / YCH)

// DPP helpers (ctrl must be literal): row_shr:1=0x111 (dst[i]=src[i-1]),
// row_shl:1=0x101 (dst[i]=src[i+1]), row_ror:N=0x120+N. Rows = 16 lanes.
#define DPPF_OLD(old, src, ctrl) \
    __int_as_float(__builtin_amdgcn_update_dpp(__float_as_int(old), __float_as_int(src), ctrl, 0xF, 0xF, false))
#define DPPF_Z(src, ctrl) \
    __int_as_float(__builtin_amdgcn_update_dpp(0, __float_as_int(src), ctrl, 0xF, 0xF, true))
#define DPPI_Z(src, ctrl) \
    __builtin_amdgcn_update_dpp(0, (int)(src), ctrl, 0xF, 0xF, true)

// ---------------------------------------------------------------------------
// Kernel 1: seam DP (R11/R13-proven, unchanged). 16 lanes per DP, dir-major
// mapping, dir1 via float4 row-segments, ballot choice-packing, runtime
// chunk loop with A/B double-buffer. Also zeroes gacc + done.
// ---------------------------------------------------------------------------
__global__ __launch_bounds__(256) void dp_kernel(const float* __restrict__ g,
                                                 int* __restrict__ paths,
                                                 unsigned long long* __restrict__ gacc,
                                                 int* __restrict__ done) {
    __shared__ uint32_t ch[16][226];   // per-row packed sel bits (b0 | b1<<16)
    __shared__ int      pth[16][226];  // backtracked path positions

    {   // zero accumulators + completion counters (label kernel runs after us)
        int t = blockIdx.x * 256 + threadIdx.x;
        if (t < BB * KK) gacc[t] = 0ull;
        if (t < BB) done[t] = 0;
    }

    const int j   = threadIdx.x & 15;
    const int grp = threadIdx.x >> 4;
    const int gid = blockIdx.x * 16 + grp;
    const int dir = gid / (BB * NSEAM);         // block-uniform (1792/16=112)
    const int rem = gid - dir * (BB * NSEAM);
    const int b   = rem / NSEAM;
    const int p   = rem - b * NSEAM;
    const int band0 = 28 * (p + 1) - BWIDTH;
    const int jc  = (j > 10) ? 10 : j;          // clamp junk lanes
    const float* gb  = g + (size_t)b * HH * WW;
    const float* gp0 = gb + band0 + jc;                 // dir0: +row*WW
    const float* gp1 = gb + (size_t)(band0 + jc) * WW;  // dir1: contiguous cols
    const int shb  = threadIdx.x & 48;          // this group's ballot slice
    const int sel0 = (j == 0) ? 1 : 0;          // sel when jm candidate wins

    float bufA[16], bufB[16], cost;

#define LOADC(BUF, c)                                                       \
    if (dir == 0) {                                                         \
        _Pragma("unroll")                                                   \
        for (int rr = 0; rr < 16; ++rr) BUF[rr] = gp0[((c) * 16 + rr) * WW];\
    } else {                                                                \
        const float4* q4 = reinterpret_cast<const float4*>(gp1 + (c) * 16); \
        float4 t0 = q4[0], t1 = q4[1], t2 = q4[2], t3 = q4[3];              \
        BUF[0] = t0.x;  BUF[1] = t0.y;  BUF[2] = t0.z;  BUF[3] = t0.w;      \
        BUF[4] = t1.x;  BUF[5] = t1.y;  BUF[6] = t1.z;  BUF[7] = t1.w;      \
        BUF[8] = t2.x;  BUF[9] = t2.y;  BUF[10] = t2.z; BUF[11] = t2.w;     \
        BUF[12] = t3.x; BUF[13] = t3.y; BUF[14] = t3.z; BUF[15] = t3.w;     \
    }

#define ROWSTEP(BUF, rr, rbase)                                             \
    {                                                                       \
        float pm  = DPPF_OLD(cost, cost, 0x111); /* prev[j-1], lane0 keeps own */  \
        float ppv = DPPF_OLD(cost, cost, 0x101); /* prev[j+1], lane15 keeps own */ \
        ppv = (j >= 10) ? cost : ppv;            /* clip at j=10 */                \
        float best = fminf(fminf(pm, cost), ppv);                           \
        int sel = (pm == best) ? sel0 : ((cost == best) ? 1 : 2);           \
        cost = best - BUF[rr];                                              \
        unsigned long long b0 = __ballot(sel & 1);                          \
        unsigned long long b1 = __ballot(sel & 2);                          \
        if (j == 0) ch[grp][(rbase) + rr] =                                 \
            (uint32_t)(((b0 >> shb) & 0xFFFFull) |                          \
                       (((b1 >> shb) & 0xFFFFull) << 16));                  \
    }

#define PROCC(BUF, cbase)                                                   \
    _Pragma("unroll")                                                       \
    for (int rr = 0; rr < 16; ++rr) ROWSTEP(BUF, rr, (cbase) * 16)

    LOADC(bufA, 0);
    LOADC(bufB, 1);
    cost = -bufA[0];
#pragma unroll
    for (int rr = 1; rr < 16; ++rr) ROWSTEP(bufA, rr, 0);
    LOADC(bufA, 2);
    PROCC(bufB, 1);
    LOADC(bufB, 3);

#pragma unroll 1
    for (int c2 = 2; c2 <= 12; c2 += 2) {
        PROCC(bufA, c2);
        if (c2 + 2 < 14) LOADC(bufA, c2 + 2);
        PROCC(bufB, c2 + 1);
        if (c2 + 3 < 14) LOADC(bufB, c2 + 3);
    }

    // final argmin across 11 lanes, first-min tie-break == lexicographic min
    float rc = (j <= 10) ? cost : INFINITY;
    int   ri = (j <= 10) ? j : 15;
#define REDSTEP(ctrl)                                                        \
    {                                                                        \
        float oc = DPPF_Z(rc, ctrl);                                         \
        int   oi = DPPI_Z(ri, ctrl);                                         \
        bool t = (oc < rc) || (oc == rc && oi < ri);                         \
        rc = t ? oc : rc; ri = t ? oi : ri;                                  \
    }
    REDSTEP(0x128) REDSTEP(0x124) REDSTEP(0x122) REDSTEP(0x121)
#undef REDSTEP

    int pos = ri;
    if (j == 0) pth[grp][HH - 1] = band0 + pos;

#pragma unroll 1
    for (int c = 13; c >= 0; --c) {
        uint32_t w[16];
#pragma unroll
        for (int rr = 0; rr < 16; ++rr) w[rr] = ch[grp][c * 16 + rr];
#pragma unroll
        for (int rr = 15; rr >= 0; --rr) {
            int r = c * 16 + rr;
            if (r >= 1) {
                uint32_t ww = w[rr];
                int sel = (int)((ww >> pos) & 1u) | (int)((ww >> (pos + 15)) & 2u);
                pos += sel - 1;
                if (j == 0) pth[grp][r - 1] = band0 + pos;
            }
        }
    }

    // coalesced path write; layout [b][dir*7+p][224]
    int* op = paths + (size_t)(b * 14 + dir * NSEAM + p) * HH;
#pragma unroll 1
    for (int c = 0; c < 14; ++c) op[c * 16 + j] = pth[grp][c * 16 + j];

#undef LOADC
#undef PROCC
#undef ROWSTEP
}

// ---------------------------------------------------------------------------
// Kernel 2: labels + centroids + fence-FREE fused finalize. Grid = B*8.
// 3-segment static walk (R13-proven, absmax=0):
//   t in [0,5]  : hl = cy-1 + (hA <= y)   (cy>=1; else 0)
//   t in [6,22] : hl = cy                 (exact)
//   t in [23,27]: hl = cy + (hB <= y)     (cy<=6; else 7)
// vl = basev + (in-band && pv[y][kv] <= x).
// Ordering WITHOUT __threadfence (R12's +52us was the fence's per-block
// cache invalidate): gacc partials, done counter, and the final re-read are
// all device-scope atomics executing at the coherence point; the
// __syncthreads() between gacc adds and done++ drains vmcnt, so the adds
// are complete at coherence before done++ issues. Last finishing block per
// image re-reads gacc via atomic fetch-add-0 and writes the centroids.
// ---------------------------------------------------------------------------
__global__ __launch_bounds__(256) void label_kernel(const int* __restrict__ paths,
                                                    float* __restrict__ out,
                                                    unsigned long long* __restrict__ gacc,
                                                    int* __restrict__ done) {
    const int b  = blockIdx.x >> 3;
    const int cy = blockIdx.x & 7;
    const int y0 = cy * YROWS;

    __shared__ unsigned char vpc[NSEAM][YROWS];  // v-seam columns for chunk
    __shared__ unsigned long long acc[KK];
    __shared__ int lastf;

    const int* pb = paths + (size_t)b * 14 * HH;
    for (int i = threadIdx.x; i < NSEAM * YROWS; i += 256) {
        int q = i / YROWS, r = i - q * YROWS;
        vpc[q][r] = (unsigned char)pb[q * HH + y0 + r];
    }
    if (threadIdx.x < KK) acc[threadIdx.x] = 0ull;
    __syncthreads();

    const int x = threadIdx.x;
    if (x < WW) {
        // v-band parameters for this column (R9-proven)
        int basev = 0, kv = 0, inv = 0;
        if (x >= 23) {
            int q = x - 23, k = q / 28, r = q - k * 28;
            if (k > 6) basev = 7;
            else { inv = (r <= 10) ? 1 : 0; basev = k + (r > 10 ? 1 : 0); kv = k; }
        }
        // the <=2 h-seam rows this chunk can cross (coalesced loads)
        const int hA = (cy >= 1) ? pb[(NSEAM + cy - 1) * HH + x] : 0;   // t 0..5
        const int hB = (cy <= 6) ? pb[(NSEAM + cy) * HH + x] : 0;       // t 23..27

        float* mb = out + (size_t)BB * KK * 2 + (size_t)b * HH * WW + x;
        int cur = -1, ys = y0;

#define FLUSH(yend)                                                          \
        {                                                                    \
            unsigned cnt = (unsigned)((yend) - ys);                          \
            unsigned sy  = (unsigned)((ys + (yend) - 1) * ((yend) - ys) / 2);\
            unsigned sx  = (unsigned)x * cnt;                                \
            atomicAdd(&acc[cur], ((unsigned long long)cnt << 42) |           \
                                 ((unsigned long long)sy << 21) |            \
                                 (unsigned long long)sx);                    \
        }

#define ROW(t, HLEXPR)                                                       \
        {                                                                    \
            const int y = y0 + (t);                                          \
            int vl = basev + ((inv && (int)vpc[kv][t] <= x) ? 1 : 0);        \
            int lab = vl + 8 * (HLEXPR);                                     \
            mb[y * WW] = (float)lab;                                         \
            if (lab != cur) { if (cur >= 0) FLUSH(y); cur = lab; ys = y; }   \
        }

#pragma unroll
        for (int t = 0; t < 6; ++t)
            ROW(t, (cy >= 1) ? (cy - 1 + ((hA <= y0 + t) ? 1 : 0)) : 0)
#pragma unroll
        for (int t = 6; t < 23; ++t)
            ROW(t, cy)
#pragma unroll
        for (int t = 23; t < 28; ++t)
            ROW(t, (cy <= 6) ? (cy + ((hB <= y0 + t) ? 1 : 0)) : 7)

        FLUSH(y0 + YROWS)
#undef ROW
#undef FLUSH
    }
    __syncthreads();

    if (threadIdx.x < KK) {
        unsigned long long v = acc[threadIdx.x];
        if (v) atomicAdd(&gacc[(size_t)b * KK + threadIdx.x], v);
    }
    __syncthreads();                 // drains vmcnt: gacc adds complete here
    if (threadIdx.x == 0)
        lastf = (atomicAdd(&done[b], 1) == YCH - 1) ? 1 : 0;
    __syncthreads();
    if (lastf && threadIdx.x < KK) {
        unsigned long long sv = atomicAdd(&gacc[(size_t)b * KK + threadIdx.x], 0ull);
        float cnt = (float)(unsigned)(sv >> 42);
        float sy  = (float)(unsigned)((sv >> 21) & 0x1FFFFFu);
        float sx  = (float)(unsigned)(sv & 0x1FFFFFu);
        float c = fmaxf(cnt, 1e-6f);
        float2 r; r.x = sy / c; r.y = sx / c;
        *reinterpret_cast<float2*>(out + (size_t)b * KK * 2 + threadIdx.x * 2) = r;
    }
}

extern "C" void kernel_launch(void* const* d_in, const int* in_sizes, int n_in,
                              void* d_out, int out_size, void* d_ws, size_t ws_size,
                              hipStream_t stream) {
    const float* g = (const float*)d_in[1];
    float* out = (float*)d_out;
    int* paths = (int*)d_ws;                                        // 3,211,264 B
    unsigned long long* gacc =
        (unsigned long long*)((char*)d_ws + (size_t)BB * 14 * HH * 4);   // 128 KiB
    int* done = (int*)((char*)d_ws + (size_t)BB * 14 * HH * 4 + BB * KK * 8);  // 1 KiB

    dp_kernel<<<(BB * 14) / 16, 256, 0, stream>>>(g, paths, gacc, done);
    label_kernel<<<BB * YCH, 256, 0, stream>>>(paths, out, gacc, done);
}

// Round 15
// 46.902 us; speedup vs baseline: 1.0717x; 1.0717x over previous
//
#include <hip/hip_runtime.h>
#include <stdint.h>

#define HH 224
#define WW 224
#define NSEAM 7
#define BWIDTH 5
#define BB 256
#define KK 64
#define YCH 8
#define YROWS (HH / YCH)

// DPP helpers (ctrl must be literal): row_shr:1=0x111 (dst[i]=src[i-1]),
// row_shl:1=0x101 (dst[i]=src[i+1]), row_ror:N=0x120+N. Rows = 16 lanes.
#define DPPF_OLD(old, src, ctrl) \
    __int_as_float(__builtin_amdgcn_update_dpp(__float_as_int(old), __float_as_int(src), ctrl, 0xF, 0xF, false))
#define DPPF_Z(src, ctrl) \
    __int_as_float(__builtin_amdgcn_update_dpp(0, __float_as_int(src), ctrl, 0xF, 0xF, true))
#define DPPI_Z(src, ctrl) \
    __builtin_amdgcn_update_dpp(0, (int)(src), ctrl, 0xF, 0xF, true)

// ---------------------------------------------------------------------------
// Kernel 1: seam DP. R13 logic with ONE change: prefetch depth 2 -> 4
// (buffers A..D; chunk-0 peeled so its row-0 init stays compile-time; loads
// issued 4 chunks (~1400-1800 cy) ahead of use, covering the ~900 cy miss
// latency that depth-2's ~700 cy did not). 16 lanes per DP, dir-major
// mapping, dir1 via float4 row-segments, ballot choice-packing. Zeroes gacc.
// ---------------------------------------------------------------------------
__global__ __launch_bounds__(256) void dp_kernel(const float* __restrict__ g,
                                                 int* __restrict__ paths,
                                                 unsigned long long* __restrict__ gacc) {
    __shared__ uint32_t ch[16][226];   // per-row packed sel bits (b0 | b1<<16)
    __shared__ int      pth[16][226];  // backtracked path positions

    {   // zero global centroid accumulators (label kernel runs after us)
        int t = blockIdx.x * 256 + threadIdx.x;
        if (t < BB * KK) gacc[t] = 0ull;
    }

    const int j   = threadIdx.x & 15;
    const int grp = threadIdx.x >> 4;
    const int gid = blockIdx.x * 16 + grp;
    const int dir = gid / (BB * NSEAM);         // block-uniform (1792/16=112)
    const int rem = gid - dir * (BB * NSEAM);
    const int b   = rem / NSEAM;
    const int p   = rem - b * NSEAM;
    const int band0 = 28 * (p + 1) - BWIDTH;
    const int jc  = (j > 10) ? 10 : j;          // clamp junk lanes
    const float* gb  = g + (size_t)b * HH * WW;
    const float* gp0 = gb + band0 + jc;                 // dir0: +row*WW
    const float* gp1 = gb + (size_t)(band0 + jc) * WW;  // dir1: contiguous cols
    const int shb  = threadIdx.x & 48;          // this group's ballot slice
    const int sel0 = (j == 0) ? 1 : 0;          // sel when jm candidate wins

    float bufA[16], bufB[16], bufC[16], bufD[16], cost;

#define LOADC(BUF, c)                                                       \
    if (dir == 0) {                                                         \
        _Pragma("unroll")                                                   \
        for (int rr = 0; rr < 16; ++rr) BUF[rr] = gp0[((c) * 16 + rr) * WW];\
    } else {                                                                \
        const float4* q4 = reinterpret_cast<const float4*>(gp1 + (c) * 16); \
        float4 t0 = q4[0], t1 = q4[1], t2 = q4[2], t3 = q4[3];              \
        BUF[0] = t0.x;  BUF[1] = t0.y;  BUF[2] = t0.z;  BUF[3] = t0.w;      \
        BUF[4] = t1.x;  BUF[5] = t1.y;  BUF[6] = t1.z;  BUF[7] = t1.w;      \
        BUF[8] = t2.x;  BUF[9] = t2.y;  BUF[10] = t2.z; BUF[11] = t2.w;     \
        BUF[12] = t3.x; BUF[13] = t3.y; BUF[14] = t3.z; BUF[15] = t3.w;     \
    }

#define ROWSTEP(BUF, rr, rbase)                                             \
    {                                                                       \
        float pm  = DPPF_OLD(cost, cost, 0x111); /* prev[j-1], lane0 keeps own */  \
        float ppv = DPPF_OLD(cost, cost, 0x101); /* prev[j+1], lane15 keeps own */ \
        ppv = (j >= 10) ? cost : ppv;            /* clip at j=10 */                \
        float best = fminf(fminf(pm, cost), ppv);                           \
        int sel = (pm == best) ? sel0 : ((cost == best) ? 1 : 2);           \
        cost = best - BUF[rr];                                              \
        unsigned long long b0 = __ballot(sel & 1);                          \
        unsigned long long b1 = __ballot(sel & 2);                          \
        if (j == 0) ch[grp][(rbase) + rr] =                                 \
            (uint32_t)(((b0 >> shb) & 0xFFFFull) |                          \
                       (((b1 >> shb) & 0xFFFFull) << 16));                  \
    }

#define PROCC(BUF, cbase)                                                   \
    _Pragma("unroll")                                                       \
    for (int rr = 0; rr < 16; ++rr) ROWSTEP(BUF, rr, (cbase) * 16)

    // prologue: fill all 4 buffers (chunks 0-3 in flight)
    LOADC(bufA, 0);
    LOADC(bufB, 1);
    LOADC(bufC, 2);
    LOADC(bufD, 3);

    // chunk 0 peeled (row-0 init is compile-time), then refill A with chunk 4
    cost = -bufA[0];
#pragma unroll
    for (int rr = 1; rr < 16; ++rr) ROWSTEP(bufA, rr, 0);
    LOADC(bufA, 4);

    // chunks 1..12 in 3 iterations of 4; buf(chunk) = chunk % 4; each buffer
    // refilled with chunk+4 immediately after consumption (4-deep pipeline)
#pragma unroll 1
    for (int c = 1; c <= 9; c += 4) {
        PROCC(bufB, c);
        if (c + 4 < 14) LOADC(bufB, c + 4);
        PROCC(bufC, c + 1);
        if (c + 5 < 14) LOADC(bufC, c + 5);
        PROCC(bufD, c + 2);
        if (c + 6 < 14) LOADC(bufD, c + 6);
        PROCC(bufA, c + 3);
        if (c + 7 < 14) LOADC(bufA, c + 7);
    }
    PROCC(bufB, 13);   // tail (loaded in the c=9 iteration)

    // final argmin across 11 lanes, first-min tie-break == lexicographic min
    float rc = (j <= 10) ? cost : INFINITY;
    int   ri = (j <= 10) ? j : 15;
#define REDSTEP(ctrl)                                                        \
    {                                                                        \
        float oc = DPPF_Z(rc, ctrl);                                         \
        int   oi = DPPI_Z(ri, ctrl);                                         \
        bool t = (oc < rc) || (oc == rc && oi < ri);                         \
        rc = t ? oc : rc; ri = t ? oi : ri;                                  \
    }
    REDSTEP(0x128) REDSTEP(0x124) REDSTEP(0x122) REDSTEP(0x121)
#undef REDSTEP

    int pos = ri;
    if (j == 0) pth[grp][HH - 1] = band0 + pos;

#pragma unroll 1
    for (int c = 13; c >= 0; --c) {
        uint32_t w[16];
#pragma unroll
        for (int rr = 0; rr < 16; ++rr) w[rr] = ch[grp][c * 16 + rr];
#pragma unroll
        for (int rr = 15; rr >= 0; --rr) {
            int r = c * 16 + rr;
            if (r >= 1) {
                uint32_t ww = w[rr];
                int sel = (int)((ww >> pos) & 1u) | (int)((ww >> (pos + 15)) & 2u);
                pos += sel - 1;
                if (j == 0) pth[grp][r - 1] = band0 + pos;
            }
        }
    }

    // coalesced path write; layout [b][dir*7+p][224]
    int* op = paths + (size_t)(b * 14 + dir * NSEAM + p) * HH;
#pragma unroll 1
    for (int c = 0; c < 14; ++c) op[c * 16 + j] = pth[grp][c * 16 + j];

#undef LOADC
#undef PROCC
#undef ROWSTEP
}

// ---------------------------------------------------------------------------
// Kernel 2: labels + centroid partials (R13-proven, unchanged). Grid = B*8;
// block = (image, 28-row chunk cy). 3-segment static walk:
//   t in [0,5]  : hl = cy-1 + (hA <= y)   (cy>=1; else 0)
//   t in [6,22] : hl = cy                 (exact)
//   t in [23,27]: hl = cy + (hB <= y)     (cy<=6; else 7)
// vl = basev + (in-band && pv[y][kv] <= x). Run-length flush -> packed u64
// LDS atomic; block partials -> global atomicAdd. Fields cnt:22@42 /
// sy:21@21 / sx:21@0, carry-free; all integers < 2^22 exact in f32.
// ---------------------------------------------------------------------------
__global__ __launch_bounds__(256) void label_kernel(const int* __restrict__ paths,
                                                    float* __restrict__ out,
                                                    unsigned long long* __restrict__ gacc) {
    const int b  = blockIdx.x >> 3;
    const int cy = blockIdx.x & 7;
    const int y0 = cy * YROWS;

    __shared__ unsigned char vpc[NSEAM][YROWS];  // v-seam columns for chunk
    __shared__ unsigned long long acc[KK];

    const int* pb = paths + (size_t)b * 14 * HH;
    for (int i = threadIdx.x; i < NSEAM * YROWS; i += 256) {
        int q = i / YROWS, r = i - q * YROWS;
        vpc[q][r] = (unsigned char)pb[q * HH + y0 + r];
    }
    if (threadIdx.x < KK) acc[threadIdx.x] = 0ull;
    __syncthreads();

    const int x = threadIdx.x;
    if (x < WW) {
        // v-band parameters for this column (R9-proven)
        int basev = 0, kv = 0, inv = 0;
        if (x >= 23) {
            int q = x - 23, k = q / 28, r = q - k * 28;
            if (k > 6) basev = 7;
            else { inv = (r <= 10) ? 1 : 0; basev = k + (r > 10 ? 1 : 0); kv = k; }
        }
        // the <=2 h-seam rows this chunk can cross (coalesced loads)
        const int hA = (cy >= 1) ? pb[(NSEAM + cy - 1) * HH + x] : 0;   // t 0..5
        const int hB = (cy <= 6) ? pb[(NSEAM + cy) * HH + x] : 0;       // t 23..27

        float* mb = out + (size_t)BB * KK * 2 + (size_t)b * HH * WW + x;
        int cur = -1, ys = y0;

#define FLUSH(yend)                                                          \
        {                                                                    \
            unsigned cnt = (unsigned)((yend) - ys);                          \
            unsigned sy  = (unsigned)((ys + (yend) - 1) * ((yend) - ys) / 2);\
            unsigned sx  = (unsigned)x * cnt;                                \
            atomicAdd(&acc[cur], ((unsigned long long)cnt << 42) |           \
                                 ((unsigned long long)sy << 21) |            \
                                 (unsigned long long)sx);                    \
        }

#define ROW(t, HLEXPR)                                                       \
        {                                                                    \
            const int y = y0 + (t);                                          \
            int vl = basev + ((inv && (int)vpc[kv][t] <= x) ? 1 : 0);        \
            int lab = vl + 8 * (HLEXPR);                                     \
            mb[y * WW] = (float)lab;                                         \
            if (lab != cur) { if (cur >= 0) FLUSH(y); cur = lab; ys = y; }   \
        }

#pragma unroll
        for (int t = 0; t < 6; ++t)
            ROW(t, (cy >= 1) ? (cy - 1 + ((hA <= y0 + t) ? 1 : 0)) : 0)
#pragma unroll
        for (int t = 6; t < 23; ++t)
            ROW(t, cy)
#pragma unroll
        for (int t = 23; t < 28; ++t)
            ROW(t, (cy <= 6) ? (cy + ((hB <= y0 + t) ? 1 : 0)) : 7)

        FLUSH(y0 + YROWS)
#undef ROW
#undef FLUSH
    }
    __syncthreads();

    if (threadIdx.x < KK) {
        unsigned long long v = acc[threadIdx.x];
        if (v) atomicAdd(&gacc[(size_t)b * KK + threadIdx.x], v);
    }
}

// ---------------------------------------------------------------------------
// Kernel 3: finalize centroids. 16384 regions; unpack, divide, float2 store.
// ---------------------------------------------------------------------------
__global__ __launch_bounds__(256) void finalize_kernel(const unsigned long long* __restrict__ gacc,
                                                       float* __restrict__ out) {
    int i = blockIdx.x * 256 + threadIdx.x;    // < BB*KK
    unsigned long long sv = gacc[i];
    float cnt = (float)(unsigned)(sv >> 42);
    float sy  = (float)(unsigned)((sv >> 21) & 0x1FFFFFu);
    float sx  = (float)(unsigned)(sv & 0x1FFFFFu);
    float c = fmaxf(cnt, 1e-6f);
    float2 r; r.x = sy / c; r.y = sx / c;
    *reinterpret_cast<float2*>(out + (size_t)i * 2) = r;
}

extern "C" void kernel_launch(void* const* d_in, const int* in_sizes, int n_in,
                              void* d_out, int out_size, void* d_ws, size_t ws_size,
                              hipStream_t stream) {
    const float* g = (const float*)d_in[1];
    float* out = (float*)d_out;
    int* paths = (int*)d_ws;                                        // 3,211,264 B
    unsigned long long* gacc =
        (unsigned long long*)((char*)d_ws + (size_t)BB * 14 * HH * 4);   // 128 KiB

    dp_kernel<<<(BB * 14) / 16, 256, 0, stream>>>(g, paths, gacc);
    label_kernel<<<BB * YCH, 256, 0, stream>>>(paths, out, gacc);
    finalize_kernel<<<(BB * KK) / 256, 256, 0, stream>>>(gacc, out);
}